// Round 8
// baseline (308.846 us; speedup 1.0000x reference)
//
#include <hip/hip_runtime.h>
#include <hip/hip_fp16.h>

// ForwardDeformer (B=4, N=250000, J=55, vol [55,16,64,64]).
// R1: pre-blend voxel grid with matrices (linearity) -> per-voxel 4x4 mats.
// R5: team=point lane=batch, 111.6us — DS-storm bound (matrices via LDS).
// R7-R12: batch=wave structure: wave w = batch w, matrices wave-uniform ->
//     s_load + v_fma(SGPR), zero matrix traffic. Traffic at compulsory floor
//     (FETCH ~115MB / WRITE ~74MB). Occupancy law: waves/CU ~= 768/VGPR.
//     R12 (VGPR 60, 12 waves/CU): 116us — but doubling occupancy only
//     bought 12% => issue-efficiency bound, not occupancy.
// R13 insight: R8's "branch-uniform waves" was FALSE in this layout — a wave
//     covers all 64 window points, mask varies per LANE, so the intra-wave
//     sort did nothing: EVERY wave executed BOTH bodies under exec-mask
//     (~2x issue cost, 50% lane efficiency). Fix: 256-pt window per block,
//     block-wide masked-first sort (LDS perm), each wave loops 4 chunks of
//     64 sorted points. Uniform chunks skip the other body via execz;
//     at most 1 boundary chunk diverges. Matrices stay SGPR.

#define JNT 55
#define VD  16
#define VH  64
#define VW  64
#define NVOX (VD * VH * VW)   // 65536

typedef float f4u __attribute__((ext_vector_type(4), aligned(4)));

// ---------------------------------------------------------------------------
// Pre-pass: tab[(b*NVOX+v)] = 64B entry { half Mi[16], half Mv_b[16] }.
// ---------------------------------------------------------------------------
__global__ __launch_bounds__(256) void build_tab_k(
    const float* __restrict__ vol, const float* __restrict__ tfs,
    const float* __restrict__ tfs_inv, __half* __restrict__ tab)
{
    int v = blockIdx.x * 256 + threadIdx.x;
    int b = blockIdx.y;
    if (v >= NVOX) return;

    float Mi[16], Mv[16];
#pragma unroll
    for (int i = 0; i < 16; ++i) { Mi[i] = 0.f; Mv[i] = 0.f; }
    const float* tb = tfs + (size_t)b * JNT * 16;
#pragma unroll 1
    for (int j = 0; j < JNT; ++j) {
        float wj = vol[j * NVOX + v];
#pragma unroll
        for (int i = 0; i < 16; ++i) Mi[i] = fmaf(wj, tfs_inv[j * 16 + i], Mi[i]);
#pragma unroll
        for (int i = 0; i < 16; ++i) Mv[i] = fmaf(wj, tb[j * 16 + i], Mv[i]);
    }
    float h[16];
#pragma unroll
    for (int i = 0; i < 8; ++i)
        h[i] = __builtin_bit_cast(float, __floats2half2_rn(Mi[2*i], Mi[2*i+1]));
#pragma unroll
    for (int i = 0; i < 8; ++i)
        h[8+i] = __builtin_bit_cast(float, __floats2half2_rn(Mv[2*i], Mv[2*i+1]));

    float4* d4 = (float4*)(tab + ((size_t)b * NVOX + v) * 32);
    d4[0] = make_float4(h[0],  h[1],  h[2],  h[3]);
    d4[1] = make_float4(h[4],  h[5],  h[6],  h[7]);
    d4[2] = make_float4(h[8],  h[9],  h[10], h[11]);
    d4[3] = make_float4(h[12], h[13], h[14], h[15]);
}

// Accumulate 8 fp16 values (one float4 of packed half2) into a[0..7].
__device__ __forceinline__ void acc8(float cw, float4 r, float* a)
{
    float rr[4] = {r.x, r.y, r.z, r.w};
#pragma unroll
    for (int kk = 0; kk < 4; ++kk) {
        __half2 h = __builtin_bit_cast(__half2, rr[kk]);
        float2 f = __half22float2(h);
        a[2*kk]     = fmaf(cw, f.x, a[2*kk]);
        a[2*kk + 1] = fmaf(cw, f.y, a[2*kk + 1]);
    }
}

__device__ __forceinline__ void epilogue(
    int b, int n, int N, float x, float y, float z,
    const float* A, const float* Ai,
    const float* __restrict__ shoff, const float* __restrict__ pooff,
    const float* __restrict__ poori,
    float* __restrict__ out_xd, float* __restrict__ out_w)
{
    size_t pid = (size_t)b * N + n;
    size_t p3  = pid * 3;
    size_t n3  = (size_t)n * 3;
    float c0 = Ai[0]*x + Ai[1]*y + Ai[2]*z  + Ai[3];
    float c1 = Ai[4]*x + Ai[5]*y + Ai[6]*z  + Ai[7];
    float c2 = Ai[8]*x + Ai[9]*y + Ai[10]*z + Ai[11];
    float sx = c0 - poori[n3 + 0] + shoff[p3 + 0] + pooff[p3 + 0];
    float sy = c1 - poori[n3 + 1] + shoff[p3 + 1] + pooff[p3 + 1];
    float sz = c2 - poori[n3 + 2] + shoff[p3 + 2] + pooff[p3 + 2];
    out_xd[p3 + 0] = A[0]*sx + A[1]*sy + A[2]*sz  + A[3];
    out_xd[p3 + 1] = A[4]*sx + A[5]*sy + A[6]*sz  + A[7];
    out_xd[p3 + 2] = A[8]*sx + A[9]*sy + A[10]*sz + A[11];

    float4* ow = (float4*)(out_w + pid * 16);
#pragma unroll
    for (int i = 0; i < 4; ++i) {
        float a0 = A[i*4+0], a1 = A[i*4+1], a2 = A[i*4+2], a3 = A[i*4+3];
        float4 r;
        r.x = a0*Ai[0] + a1*Ai[4] + a2*Ai[8]  + a3*Ai[12];
        r.y = a0*Ai[1] + a1*Ai[5] + a2*Ai[9]  + a3*Ai[13];
        r.z = a0*Ai[2] + a1*Ai[6] + a2*Ai[10] + a3*Ai[14];
        r.w = a0*Ai[3] + a1*Ai[7] + a2*Ai[11] + a3*Ai[15];
        ow[i] = r;
    }
}

// ---------------------------------------------------------------------------
// Main kernel: block = 4 waves over a 256-POINT window; wave w = batch w
// (b = readfirstlane -> SGPR matrices). Block-wide masked-first sort of the
// 256 points (LDS perm); each wave loops 4 chunks of 64 sorted points.
// Uniform chunks execute exactly ONE body (execz skips the other); at most
// one boundary chunk diverges. No VGPR caps (caps -> spill, R8/R9).
// ---------------------------------------------------------------------------
template <int B>
__global__ __launch_bounds__(256) void main_k(
    const float* __restrict__ xc,
    const float* __restrict__ shoff,
    const float* __restrict__ pooff,
    const float* __restrict__ tfs,        // [B, J, 16]
    const float* __restrict__ tfs_inv,    // [J, 16]
    const float* __restrict__ poori,      // [N, 3]
    const float* __restrict__ lbsw,       // [N, J]
    const int*   __restrict__ mask,       // [N]
    const __half* __restrict__ tab,       // [B, NVOX, 32 halves]
    const float* __restrict__ offk,
    const float* __restrict__ sck,
    float* __restrict__ out_xd,
    float* __restrict__ out_w,
    int N)
{
    __shared__ unsigned short sPerm[256];
    __shared__ int sCnt[4];

    int tx = threadIdx.x;
    int ln = tx & 63;
    int wv = tx >> 6;
    int b  = __builtin_amdgcn_readfirstlane(wv);   // wave-uniform batch
    int base = blockIdx.x * 256;

    // ---- block-wide mask partition over 256 points (masked first) ---------
    {
        int n0 = base + tx;
        bool mm = (n0 < N) && (mask[n0] != 0);
        unsigned long long bal = __ballot(mm);
        int cm = __popcll(bal);
        if (ln == 0) sCnt[wv] = cm;
        __syncthreads();
        int c0 = sCnt[0], c1 = sCnt[1], c2 = sCnt[2], c3 = sCnt[3];
        int totM  = c0 + c1 + c2 + c3;
        int mBase = (wv > 0 ? c0 : 0) + (wv > 1 ? c1 : 0) + (wv > 2 ? c2 : 0);
        unsigned long long below = bal & ((1ull << ln) - 1ull);
        int rm  = __popcll(below);
        int pos = mm ? (mBase + rm) : (totM + (wv * 64 - mBase) + (ln - rm));
        sPerm[pos] = (unsigned short)tx;
        if (tx == 0) sCnt[0] = totM;   // reuse slot 0 for total
        __syncthreads();
    }
    int totM = sCnt[0];

    float o0 = offk[0], o1 = offk[1], o2 = offk[2];
    float s0 = sck[0],  s1 = sck[1],  s2 = sck[2];
    const float*  tb  = tfs + (size_t)b * JNT * 16;
    const __half* tbb = tab + (size_t)b * NVOX * 32;

#pragma unroll 1
    for (int c = 0; c < 4; ++c) {
        int r   = c * 64 + ln;               // sorted rank of this lane's point
        int slot = sPerm[r];
        int n = base + slot;
        bool m = (r < totM);                 // chunk-sorted: uniform for 3/4 chunks
        if (n >= N) continue;                // tail lanes (last block only)

        size_t p3 = ((size_t)b * N + n) * 3;
        float x = xc[p3], y = xc[p3 + 1], z = xc[p3 + 2];

        float A[16], Ai[16];
#pragma unroll
        for (int i = 0; i < 16; ++i) { A[i] = 0.f; Ai[i] = 0.f; }

        if (m) {
            // ---- masked: matrices wave-uniform -> s_load + v_fma(SGPR) ----
            const float* row = lbsw + (size_t)n * JNT;
#pragma unroll 1
            for (int jj = 0; jj < 13; ++jj) {
                f4u w4 = *(const f4u*)(row + 4 * jj);
                float wq[4] = {w4.x, w4.y, w4.z, w4.w};
#pragma unroll
                for (int q = 0; q < 4; ++q) {
                    int j = 4 * jj + q;
                    float wj = wq[q];
#pragma unroll
                    for (int i = 0; i < 16; ++i) Ai[i] = fmaf(wj, tfs_inv[j*16+i], Ai[i]);
#pragma unroll
                    for (int i = 0; i < 16; ++i) A[i]  = fmaf(wj, tb[j*16+i],      A[i]);
                }
            }
#pragma unroll 1
            for (int j = 52; j < JNT; ++j) {
                float wj = row[j];
#pragma unroll
                for (int i = 0; i < 16; ++i) Ai[i] = fmaf(wj, tfs_inv[j*16+i], Ai[i]);
#pragma unroll
                for (int i = 0; i < 16; ++i) A[i]  = fmaf(wj, tb[j*16+i],      A[i]);
            }
        } else {
            // ---- unmasked: 8-corner gather of own 64B tab entry -----------
            float px = (x + o0) * s0;
            float py = (y + o1) * s1;
            float pz = (z + o2) * s2;
            float ix = fminf(fmaxf((px + 1.f) * 0.5f * (VW - 1), 0.f), (float)(VW - 1));
            float iy = fminf(fmaxf((py + 1.f) * 0.5f * (VH - 1), 0.f), (float)(VH - 1));
            float iz = fminf(fmaxf((pz + 1.f) * 0.5f * (VD - 1), 0.f), (float)(VD - 1));
            float fx = floorf(ix), fy = floorf(iy), fz = floorf(iz);
            float wx = ix - fx,    wy = iy - fy,    wz = iz - fz;
            int x0 = (int)fx, y0 = (int)fy, z0 = (int)fz;
            int x1 = min(x0 + 1, VW - 1);
            int y1 = min(y0 + 1, VH - 1);
            int z1 = min(z0 + 1, VD - 1);

#pragma unroll 2
            for (int cc = 0; cc < 8; ++cc) {
                int zc  = (cc & 4) ? z1 : z0;
                int yc  = (cc & 2) ? y1 : y0;
                int xcc = (cc & 1) ? x1 : x0;
                float cw = ((cc & 4) ? wz : 1.f - wz)
                         * ((cc & 2) ? wy : 1.f - wy)
                         * ((cc & 1) ? wx : 1.f - wx);
                int vox = (zc * VH + yc) * VW + xcc;
                const float4* e = (const float4*)(tbb + (size_t)vox * 32);
                float4 e0 = e[0], e1 = e[1], e2 = e[2], e3 = e[3];
                acc8(cw, e0, Ai);
                acc8(cw, e1, Ai + 8);
                acc8(cw, e2, A);
                acc8(cw, e3, A + 8);
            }
        }

        epilogue(b, n, N, x, y, z, A, Ai, shoff, pooff, poori, out_xd, out_w);
    }
}

// ---------------------------------------------------------------------------
// Fallback (ws too small or B != 4): per-thread direct gather from vol.
// ---------------------------------------------------------------------------
__global__ __launch_bounds__(256) void fb_k(
    const float* __restrict__ xc, const float* __restrict__ shoff,
    const float* __restrict__ pooff, const float* __restrict__ tfs,
    const float* __restrict__ tfs_inv, const float* __restrict__ poori,
    const float* __restrict__ lbsw, const int* __restrict__ mask,
    const float* __restrict__ vol, const float* __restrict__ offk,
    const float* __restrict__ sck, float* __restrict__ out_xd,
    float* __restrict__ out_w, int N)
{
    int n = blockIdx.x * 256 + threadIdx.x;
    int b = blockIdx.y;
    if (n >= N) return;
    size_t p3 = ((size_t)b * N + n) * 3;
    float x = xc[p3], y = xc[p3 + 1], z = xc[p3 + 2];
    float A[16], Ai[16];
#pragma unroll
    for (int i = 0; i < 16; ++i) { A[i] = 0.f; Ai[i] = 0.f; }
    const float* tb = tfs + (size_t)b * JNT * 16;

    if (mask[n] != 0) {
        const float* lp = lbsw + (size_t)n * JNT;
#pragma unroll 1
        for (int j = 0; j < JNT; ++j) {
            float wj = lp[j];
#pragma unroll
            for (int i = 0; i < 16; ++i) Ai[i] = fmaf(wj, tfs_inv[j*16+i], Ai[i]);
#pragma unroll
            for (int i = 0; i < 16; ++i) A[i]  = fmaf(wj, tb[j*16+i],      A[i]);
        }
    } else {
        float px = (x + offk[0]) * sck[0];
        float py = (y + offk[1]) * sck[1];
        float pz = (z + offk[2]) * sck[2];
        float ix = fminf(fmaxf((px + 1.f) * 0.5f * (VW - 1), 0.f), (float)(VW - 1));
        float iy = fminf(fmaxf((py + 1.f) * 0.5f * (VH - 1), 0.f), (float)(VH - 1));
        float iz = fminf(fmaxf((pz + 1.f) * 0.5f * (VD - 1), 0.f), (float)(VD - 1));
        float fx = floorf(ix), fy = floorf(iy), fz = floorf(iz);
        float wx = ix - fx, wy = iy - fy, wz = iz - fz;
        int x0 = (int)fx, y0 = (int)fy, z0 = (int)fz;
        int x1 = min(x0 + 1, VW - 1);
        int y1 = min(y0 + 1, VH - 1);
        int z1 = min(z0 + 1, VD - 1);
        float w00 = (1.f - wz) * (1.f - wy), w01 = (1.f - wz) * wy;
        float w10 = wz * (1.f - wy),         w11 = wz * wy;
        int o00 = (z0 * VH + y0) * VW, o01 = (z0 * VH + y1) * VW;
        int o10 = (z1 * VH + y0) * VW, o11 = (z1 * VH + y1) * VW;
#pragma unroll 1
        for (int j = 0; j < JNT; ++j) {
            const float* vp = vol + (size_t)j * NVOX;
            float v000 = vp[o00 + x0], v001 = vp[o00 + x1];
            float v010 = vp[o01 + x0], v011 = vp[o01 + x1];
            float v100 = vp[o10 + x0], v101 = vp[o10 + x1];
            float v110 = vp[o11 + x0], v111 = vp[o11 + x1];
            float c0 = w00 * v000 + w01 * v010 + w10 * v100 + w11 * v110;
            float c1 = w00 * v001 + w01 * v011 + w10 * v101 + w11 * v111;
            float wj = c0 + wx * (c1 - c0);
#pragma unroll
            for (int i = 0; i < 16; ++i) Ai[i] = fmaf(wj, tfs_inv[j*16+i], Ai[i]);
#pragma unroll
            for (int i = 0; i < 16; ++i) A[i]  = fmaf(wj, tb[j*16+i],      A[i]);
        }
    }
    epilogue(b, n, N, x, y, z, A, Ai, shoff, pooff, poori, out_xd, out_w);
}

extern "C" void kernel_launch(void* const* d_in, const int* in_sizes, int n_in,
                              void* d_out, int out_size, void* d_ws, size_t ws_size,
                              hipStream_t stream)
{
    const float* xc    = (const float*)d_in[0];
    const float* shoff = (const float*)d_in[1];
    const float* pooff = (const float*)d_in[2];
    const float* tfs   = (const float*)d_in[3];
    const float* tfsi  = (const float*)d_in[4];
    const float* poori = (const float*)d_in[5];
    const float* lbsw  = (const float*)d_in[6];
    const int*   mask  = (const int*)d_in[7];
    const float* vol   = (const float*)d_in[8];
    const float* offk  = (const float*)d_in[9];
    const float* sck   = (const float*)d_in[10];

    int N = in_sizes[5] / 3;          // poseoff_ori [1,N,3]
    int B = in_sizes[0] / (3 * N);    // xc [B,N,3]
    float* out_xd = (float*)d_out;
    float* out_w  = (float*)d_out + (size_t)B * N * 3;

    size_t tab_bytes = (size_t)B * NVOX * 32 * sizeof(__half);  // 16.78 MB
    __half* tab = (__half*)d_ws;

    if (B == 4 && ws_size >= tab_bytes) {
        build_tab_k<<<dim3((NVOX + 255) / 256, 4), dim3(256), 0, stream>>>(
            vol, tfs, tfsi, tab);
        main_k<4><<<dim3((N + 255) / 256), dim3(256), 0, stream>>>(
            xc, shoff, pooff, tfs, tfsi, poori, lbsw, mask, tab,
            offk, sck, out_xd, out_w, N);
    } else {
        fb_k<<<dim3((N + 255) / 256, B), dim3(256), 0, stream>>>(
            xc, shoff, pooff, tfs, tfsi, poori, lbsw, mask, vol, offk, sck,
            out_xd, out_w, N);
    }
}